// Round 10
// baseline (179.026 us; speedup 1.0000x reference)
//
#include <hip/hip_runtime.h>
#include <math.h>

typedef unsigned int u32;
typedef unsigned long long u64;

#define NPIX 6291456

// ---------------- buffers ----------------
// ws:
//     0: madsum f32         (zeroed by hist_kernel, atomicAdd by denoise)
//   384: selBin[32] u32     (written by extract_kernel s==0 blocks)
//   512: selKr[32] u32
//  1024: arts, 4 bf16 planes of NPIX packed as u32[2*NPIX] = 50.33 MB
// d_out (25.2 MB) doubles as median scratch — dead until fuse overwrites it:
//     hist    = out + 0      : [32][8][4096] u32 = 4 MB
//     members = out + 4 MB   : [32][8][8192] u32 = 8 MB
//     scount  = out + 12 MB  : [256] u32
//   (denoise reads members while writing arts — disjoint buffers, no alias)
//
// Sync-cost ledger (measured): dispatch boundary ~12us; per-block
// __threadfence protocol ~90us (R8); grid.sync ~94us/sync (R5); 768-block
// atomic spin barrier ~280us (R6). => kernel boundaries ONLY; redundant
// per-block recomputation beats any cross-block handoff.
// Spill ledger (R7): duplicated pipeline bodies => ~1GB scratch traffic.
// Occupancy ledger (R9): denoise is VALU-bound, not latency-bound —
// seg16 (40% occ) = 76.4us vs seg32 (24% occ) = 73us. Keep seg32.

__device__ __forceinline__ float med3f(float a, float b, float c) {
    return fmaxf(fminf(a, b), fminf(fmaxf(a, b), c));
}
__device__ __forceinline__ float med5f(float a0, float a1, float a2, float a3, float a4) {
    float mn01 = fminf(a0, a1), mx01 = fmaxf(a0, a1);
    float mn34 = fminf(a3, a4), mx34 = fmaxf(a3, a4);
    return med3f(a2, fmaxf(mn01, mn34), fminf(mx01, mx34));
}
__device__ __forceinline__ u32 packbf(float lo, float hi) {
    u32 a = __float_as_uint(lo), b = __float_as_uint(hi);
    a = (a + 0x7FFFu + ((a >> 16) & 1u)) >> 16;
    b = (b + 0x7FFFu + ((b >> 16) & 1u)) >> 16;
    return a | (b << 16);
}

// inclusive scan over 1024 threads; wtot = 16-entry LDS; all threads must call
__device__ __forceinline__ u32 scan1024(u32 v, u32* wtot) {
    int lane = threadIdx.x & 63, wid = threadIdx.x >> 6;
    u32 inc = v;
    #pragma unroll
    for (int off = 1; off < 64; off <<= 1) {
        u32 o = __shfl_up(inc, off);
        if (lane >= off) inc += o;
    }
    __syncthreads();                 // WAR protection for wtot reuse
    if (lane == 63) wtot[wid] = inc;
    __syncthreads();
    for (int w = 0; w < wid; ++w) inc += wtot[w];
    return inc;
}

// inclusive scan over 256 threads (4 waves); wtot = 4-entry LDS
__device__ __forceinline__ u32 scan256(u32 v, u32* wtot) {
    int lane = threadIdx.x & 63, wid = threadIdx.x >> 6;
    u32 inc = v;
    #pragma unroll
    for (int off = 1; off < 64; off <<= 1) {
        u32 o = __shfl_up(inc, off);
        if (lane >= off) inc += o;
    }
    __syncthreads();
    if (lane == 63) wtot[wid] = inc;
    __syncthreads();
    for (int w = 0; w < wid; ++w) inc += wtot[w];
    return inc;
}

// ---------------- median stage 1: per-slice 12-bit histograms ----------------
// 256 blocks = 32 batches x 8 slices; each slice = 24576 floats.

__global__ __launch_bounds__(1024) void hist_kernel(
        const float* __restrict__ x, u32* __restrict__ hist,
        float* __restrict__ madsum) {
    __shared__ u32 lh[16400];    // 4*4100 (lane-spread subs, +4 pad)
    int b = blockIdx.x >> 3, s = blockIdx.x & 7, t = threadIdx.x;
    uint4 z = make_uint4(0u, 0u, 0u, 0u);
    #pragma unroll
    for (int j = 0; j < 4; ++j) ((uint4*)lh)[t + j * 1024] = z;
    if (t < 4) ((uint4*)lh)[4096 + t] = z;
    __syncthreads();
    const float4* xb = (const float4*)(x + (size_t)b * 196608 + s * 24576);
    u32 sub = (u32)(t & 3) * 4100u;
    #pragma unroll
    for (int i = 0; i < 6; ++i) {
        float4 v = xb[t + i * 1024];
        atomicAdd(&lh[sub + (__float_as_uint(fabsf(v.x)) >> 19)], 1u);
        atomicAdd(&lh[sub + (__float_as_uint(fabsf(v.y)) >> 19)], 1u);
        atomicAdd(&lh[sub + (__float_as_uint(fabsf(v.z)) >> 19)], 1u);
        atomicAdd(&lh[sub + (__float_as_uint(fabsf(v.w)) >> 19)], 1u);
    }
    __syncthreads();
    // write bins 4t..4t+3 (sum of 4 subs) as one uint4 — conflict-free reads
    u32 a0 = 0, a1 = 0, a2 = 0, a3 = 0;
    #pragma unroll
    for (int sb = 0; sb < 4; ++sb) {
        uint4 hv = *(const uint4*)&lh[sb * 4100u + (u32)t * 4u];
        a0 += hv.x; a1 += hv.y; a2 += hv.z; a3 += hv.w;
    }
    u32* hb = hist + ((size_t)b * 8 + s) * 4096;
    ((uint4*)hb)[t] = make_uint4(a0, a1, a2, a3);
    if (s == 0 && t == 0 && b == 0) *madsum = 0.0f;
}

// ---------------- median stage 2: find bin, extract member suffixes ----------
// LDS ballot-compaction then ONE coalesced write-out per block. No global
// atomics, no fences — visibility to denoise via the kernel boundary.

__global__ __launch_bounds__(1024) void extract_kernel(
        const float* __restrict__ x, const u32* __restrict__ hist,
        u32* __restrict__ members, u32* __restrict__ scount,
        u32* __restrict__ selBin, u32* __restrict__ selKr) {
    __shared__ u32 sbuf[8192];
    __shared__ u32 wtot[16];
    __shared__ u32 sBin, lcnt;
    int b = blockIdx.x >> 3, s = blockIdx.x & 7, t = threadIdx.x, lane = t & 63;
    if (t == 0) lcnt = 0u;
    // sum the 8 slice histograms: thread t owns bins 4t..4t+3
    const u32* hb = hist + (size_t)b * 32768;
    u32 s4[4] = {0u, 0u, 0u, 0u};
    #pragma unroll
    for (int sl = 0; sl < 8; ++sl) {
        uint4 h4 = ((const uint4*)(hb + sl * 4096))[t];
        s4[0] += h4.x; s4[1] += h4.y; s4[2] += h4.z; s4[3] += h4.w;
    }
    u32 sum = s4[0] + s4[1] + s4[2] + s4[3];
    u32 inc = scan1024(sum, wtot);
    u32 exc = inc - sum;
    u32 k = 98303u;                  // lower median rank of 196608
    if (exc <= k && k < inc) {
        u32 kr = k - exc;
        int j = 0;
        while (kr >= s4[j]) { kr -= s4[j]; ++j; }
        sBin = (u32)(t * 4 + j);
        if (s == 0) { selBin[b] = (u32)(t * 4 + j); selKr[b] = kr; }
    }
    __syncthreads();
    u32 bin = sBin;
    // sweep the slice (L2/L3-warm from stage 1): ballot-compact 19-bit suffixes
    const float4* xb = (const float4*)(x + (size_t)b * 196608 + s * 24576);
    #pragma unroll 2
    for (int i = 0; i < 6; ++i) {
        float4 v = xb[t + i * 1024];
        float vv[4] = {v.x, v.y, v.z, v.w};
        #pragma unroll
        for (int e = 0; e < 4; ++e) {
            u32 bits = __float_as_uint(fabsf(vv[e]));
            bool is = (bits >> 19) == bin;
            u64 ball = __ballot(is);
            if (ball) {
                u32 cnt = (u32)__popcll(ball);
                u32 base = 0;
                if (lane == 0) base = atomicAdd(&lcnt, cnt);
                base = __shfl(base, 0);
                if (is) {
                    u32 p = base + (u32)__popcll(ball & ((1ull << lane) - 1ull));
                    if (p < 8192u) sbuf[p] = bits & 0x7FFFFu;
                }
            }
        }
    }
    __syncthreads();
    u32 cnt = lcnt; if (cnt > 8192u) cnt = 8192u;
    u32* mb = members + ((size_t)b * 8 + s) * 8192;
    for (u32 i = (u32)t; i < cnt; i += 1024u) mb[i] = sbuf[i];
    if (t == 0) scount[b * 8 + s] = cnt;
}

// ---------------- denoise (seg=32) with per-block inline radix select --------
// identity: huber_tv(x/s, lam, del) * s == huber_tv(x, lam*s, del*s)
// Each block redundantly radix-selects its batch's median suffix from the
// L2-hot members arrays (3 read-only counting passes — order-independent,
// bit-exact vs the old select_kernel incl. the 8192 positional cap). Zero
// cross-block communication.

__device__ __forceinline__ float dpp_shl1(float v) {   // lane i <- lane i+1 (edge -> 0)
    return __uint_as_float((u32)__builtin_amdgcn_update_dpp(
        0, (int)__float_as_uint(v), 0x130, 0xF, 0xF, true));   // wave_shl:1
}
__device__ __forceinline__ float dpp_shr1(float v) {   // lane i <- lane i-1 (edge -> 0)
    return __uint_as_float((u32)__builtin_amdgcn_update_dpp(
        0, (int)__float_as_uint(v), 0x138, 0xF, 0xF, true));   // wave_shr:1
}
__device__ __forceinline__ float hub(float d, float del) {
    return d * __builtin_amdgcn_rcpf(del + fabsf(d));
}
__device__ __forceinline__ float upd(float b, float xn, float dv, float lam) {
    float t = fmaf(-lam, dv, b - xn);
    return fmaf(-0.2f, t, b);
}

__device__ __forceinline__ float4 stage4(float4 B, float4 C, float4 xn, float4& gyp,
                                         int row, float mR3, float mL0,
                                         float lam, float del) {
    float mr = (row < 255) ? 1.f : 0.f;   // wave-uniform: dy pad 0 at last row
    float m0 = (row == 0) ? 0.f : 1.f;    // div_y[0] = gy[0]
    float gy0 = hub(C.x - B.x, del) * mr;
    float gy1 = hub(C.y - B.y, del) * mr;
    float gy2 = hub(C.z - B.z, del) * mr;
    float gy3 = hub(C.w - B.w, del) * mr;
    float dv0 = gy0 - gyp.x * m0;
    float dv1 = gy1 - gyp.y * m0;
    float dv2 = gy2 - gyp.z * m0;
    float dv3 = gy3 - gyp.w * m0;
    gyp.x = gy0; gyp.y = gy1; gyp.z = gy2; gyp.w = gy3;
    float B0n = dpp_shl1(B.x);                  // next lane's col0 (= own col3+1)
    float g01 = hub(B.y - B.x, del);
    float g12 = hub(B.z - B.y, del);
    float g23 = hub(B.w - B.z, del);
    float g3n = hub(B0n - B.w, del) * mR3;      // 0 at global col 255
    float gp  = dpp_shr1(g3n) * mL0;            // prev lane's g3n; div_x[0] = gx[0]
    float4 o;
    o.x = upd(B.x, xn.x, (g01 - gp)  + dv0, lam);
    o.y = upd(B.y, xn.y, (g12 - g01) + dv1, lam);
    o.z = upd(B.z, xn.z, (g3n - g23) + dv3, lam);   // placeholder (fixed below)
    o.w = 0.f;
    // NOTE: components assigned explicitly below to avoid any reorder typo
    o.z = upd(B.z, xn.z, (g23 - g12) + dv2, lam);
    o.w = upd(B.w, xn.w, (g3n - g23) + dv3, lam);
    return o;
}

__global__ __launch_bounds__(256, 6) void denoise_kernel(
        const float* __restrict__ x, const u32* __restrict__ selBin,
        const u32* __restrict__ selKr, const u32* __restrict__ scount,
        const u32* __restrict__ members, u32* __restrict__ arts,
        float* __restrict__ madsum, float4 lam4, float4 del4) {
    __shared__ float sex[2][5][256];   // double-buffered: [parity][0]=x,[1..4]=views
    __shared__ float red[4];
    __shared__ u32 h[128];
    __shared__ u32 wt4[4];
    __shared__ u32 sPfx, sK;
    int t = threadIdx.x, lane = t & 63, wid = t >> 6;   // wid = view
    int img = blockIdx.x >> 3;       // 96 images
    int seg = blockIdx.x & 7;        // 8 row-segments of 32 rows
    int b = img / 3;

    // ---- inline radix select (redundant per block, counting-only) ----
    u32 bin = selBin[b];
    u32 c8[8];
    #pragma unroll
    for (int sl = 0; sl < 8; ++sl) c8[sl] = scount[b * 8 + sl];
    if (t == 0) { sPfx = 0u; sK = selKr[b]; }
    __syncthreads();
    {
        const int shf[3] = {12, 6, 0};
        const int wd[3]  = {7, 6, 6};
        const u32 msk[3] = {127u, 63u, 63u};
        #pragma unroll 1
        for (int rd = 0; rd < 3; ++rd) {
            u32 pfx = sPfx, k2 = sK;
            if (t < 128) h[t] = 0u;
            __syncthreads();
            u32 off = 0u;
            #pragma unroll
            for (int sl = 0; sl < 8; ++sl) {
                u32 lim = c8[sl];
                if (off >= 8192u) lim = 0u;                 // positional cap
                else if (off + lim > 8192u) lim = 8192u - off;
                const u32* mb = members + ((size_t)b * 8 + sl) * 8192;
                for (u32 i = (u32)t; i < lim; i += 256u) {
                    u32 v = mb[i];
                    if ((v >> (shf[rd] + wd[rd])) == pfx)
                        atomicAdd(&h[(v >> shf[rd]) & msk[rd]], 1u);
                }
                off += c8[sl];
            }
            __syncthreads();
            u32 nb = msk[rd] + 1u;
            u32 cc = ((u32)t < nb) ? h[t] : 0u;
            u32 inc2 = scan256(cc, wt4);
            u32 exc2 = inc2 - cc;
            if ((u32)t < nb && exc2 <= k2 && k2 < inc2) {
                sPfx = (pfx << wd[rd]) | (u32)t;
                sK = k2 - exc2;
            }
            __syncthreads();
        }
    }
    float sc = __uint_as_float((bin << 19) | sPfx) + 1e-8f;

    // ---- denoise main (exact R4 structure) ----
    float lam = ((wid == 0) ? lam4.x : (wid == 1) ? lam4.y : (wid == 2) ? lam4.z : lam4.w) * sc;
    float del = ((wid == 0) ? del4.x : (wid == 1) ? del4.y : (wid == 2) ? del4.z : del4.w) * sc;
    float mR3 = (lane == 63) ? 0.f : 1.f;
    float mL0 = (lane == 0) ? 0.f : 1.f;
    const float4* xp = (const float4*)(x + (size_t)img * 65536) + lane;  // row r: xp[r<<6]
    u32* ap = arts + (size_t)wid * (NPIX / 2) + (size_t)img * 32768 + lane * 2;

    float4 z4 = {0.f, 0.f, 0.f, 0.f};
    float4 cur1 = z4, cur2 = z4, gyp1 = z4, gyp2 = z4, gyp3 = z4;
    float4 n0 = z4, n1 = z4, n2 = z4;
    int out_lo = seg * 32, out_hi = out_lo + 31;
    int rs = (out_lo >= 3) ? out_lo - 3 : 0;   // 3-row pipeline warm-up
    int rend = out_hi + 3;                     // 3-step flush
    float msum = 0.f;

    float4 nl = xp[rs << 6];
    for (int r = rs; r <= rend; ++r) {
        int rn = (r + 1 <= 255) ? r + 1 : 255;
        float4 nxt = xp[rn << 6];   // prefetch (clamped; value unused past row 255)
        int r1 = r - 1, r2 = r - 2, r3 = r - 3;
        float4 x1 = stage4(n0,   nl, n0, gyp1, r1, mR3, mL0, lam, del);
        float4 x2 = stage4(cur1, x1, n1, gyp2, r2, mR3, mL0, lam, del);
        float4 x3 = stage4(cur2, x2, n2, gyp3, r3, mR3, mL0, lam, del);
        cur1 = x1; cur2 = x2;
        if (r3 >= out_lo) {   // block-uniform; r3 <= out_hi by loop bound
            uint2 pk;
            pk.x = packbf(x3.x, x3.y);
            pk.y = packbf(x3.z, x3.w);
            *(uint2*)(ap + (r3 << 7)) = pk;
            // mad exchange, double-buffered by row parity: one sync per row
            int pb = r3 & 1;
            *(float4*)&sex[pb][wid + 1][lane * 4] = x3;
            if (wid == 0) *(float4*)&sex[pb][0][lane * 4] = n2;
            __syncthreads();
            int c = wid * 64 + lane;
            float a0 = sex[pb][0][c], a1 = sex[pb][1][c], a2 = sex[pb][2][c],
                  a3 = sex[pb][3][c], a4 = sex[pb][4][c];
            float med = med5f(a0, a1, a2, a3, a4);
            msum += med5f(fabsf(a0 - med), fabsf(a1 - med), fabsf(a2 - med),
                          fabsf(a3 - med), fabsf(a4 - med));
        }
        n2 = n1; n1 = n0; n0 = nl;
        nl = nxt;
    }
    #pragma unroll
    for (int off = 32; off > 0; off >>= 1) msum += __shfl_down(msum, off);
    if (lane == 0) red[wid] = msum;
    __syncthreads();
    if (t == 0) atomicAdd(madsum, red[0] + red[1] + red[2] + red[3]);
}

// ---------------- fusion: 4 px/thread, 16B loads/stores ----------------

__global__ __launch_bounds__(256) void fuse_kernel(
        const float* __restrict__ x, const u32* __restrict__ artsU,
        const float* __restrict__ madsum, float* __restrict__ out) {
    int t = blockIdx.x * 256 + threadIdx.x;   // t in [0, NPIX/4)
    float floorv = 0.1f * (*madsum) * (1.0f / 6291456.0f);
    float4 xv = ((const float4*)x)[t];
    uint2 q0 = ((const uint2*)(artsU))[t];
    uint2 q1 = ((const uint2*)(artsU + NPIX / 2))[t];
    uint2 q2 = ((const uint2*)(artsU + NPIX))[t];
    uint2 q3 = ((const uint2*)(artsU + 3 * (NPIX / 2)))[t];
    float4 o;
#define FUSE1(res, A0, U0, U1, U2, U3, SH) { \
        float a0 = A0; \
        float a1 = __uint_as_float(SH(U0)), a2 = __uint_as_float(SH(U1)); \
        float a3 = __uint_as_float(SH(U2)), a4 = __uint_as_float(SH(U3)); \
        float med = med5f(a0, a1, a2, a3, a4); \
        float d0 = fabsf(a0 - med), d1 = fabsf(a1 - med), d2 = fabsf(a2 - med); \
        float d3 = fabsf(a3 - med), d4 = fabsf(a4 - med); \
        float mad = med5f(d0, d1, d2, d3, d4); \
        float mm = fmaxf(mad, floorv); \
        float inv = 0.5f / mm; \
        float w0 = __expf(-d0 * inv), w1 = __expf(-d1 * inv), w2 = __expf(-d2 * inv); \
        float w3 = __expf(-d3 * inv), w4 = __expf(-d4 * inv); \
        float swt = w0 + w1 + w2 + w3 + w4; \
        float sva = fmaf(w0, a0, fmaf(w1, a1, fmaf(w2, a2, fmaf(w3, a3, w4 * a4)))); \
        res = sva / (swt + 1e-8f); \
    }
#define LO16(u) ((u) << 16)
#define HI16(u) ((u) & 0xFFFF0000u)
    FUSE1(o.x, xv.x, q0.x, q1.x, q2.x, q3.x, LO16);
    FUSE1(o.y, xv.y, q0.x, q1.x, q2.x, q3.x, HI16);
    FUSE1(o.z, xv.z, q0.y, q1.y, q2.y, q3.y, LO16);
    FUSE1(o.w, xv.w, q0.y, q1.y, q2.y, q3.y, HI16);
#undef FUSE1
#undef LO16
#undef HI16
    ((float4*)out)[t] = o;
}

// ---------------- launch ----------------

extern "C" void kernel_launch(void* const* d_in, const int* in_sizes, int n_in,
                              void* d_out, int out_size, void* d_ws, size_t ws_size,
                              hipStream_t stream) {
    const float* x = (const float*)d_in[0];
    float* out = (float*)d_out;
    char* ws = (char*)d_ws;
    float* madsum = (float*)ws;
    u32* selBin   = (u32*)(ws + 384);
    u32* selKr    = (u32*)(ws + 512);
    u32* artsU    = (u32*)(ws + 1024);
    // median scratch lives in d_out (dead until fuse overwrites it):
    u32* hist     = (u32*)out;
    u32* members  = (u32*)out + (size_t)32 * 8 * 4096;      // +4 MB
    u32* scount   = members + (size_t)32 * 8 * 8192;        // +12 MB

    hist_kernel<<<256, 1024, 0, stream>>>(x, hist, madsum);
    extract_kernel<<<256, 1024, 0, stream>>>(x, hist, members, scount, selBin, selKr);

    float lamf[4], delf[4];
    for (int i = 0; i < 4; ++i) {
        double lam = 0.025 + 0.05 * (double)i / 3.0;
        lamf[i] = (float)lam;
        delf[i] = (float)(0.01 * sqrt(lam / (0.05 + 1e-8)));
    }
    float4 lam4 = make_float4(lamf[0], lamf[1], lamf[2], lamf[3]);
    float4 del4 = make_float4(delf[0], delf[1], delf[2], delf[3]);

    denoise_kernel<<<768, 256, 0, stream>>>(x, selBin, selKr, scount, members,
                                            artsU, madsum, lam4, del4);
    fuse_kernel<<<6144, 256, 0, stream>>>(x, artsU, madsum, out);
}

// Round 11
// 170.553 us; speedup vs baseline: 1.0497x; 1.0497x over previous
//
#include <hip/hip_runtime.h>
#include <math.h>

typedef unsigned int u32;
typedef unsigned long long u64;
typedef float v2f __attribute__((ext_vector_type(2)));

#define NPIX 6291456

// ---------------- ws layout ----------------
//     0: scale[32] f32      (written by select_kernel)
//   128: madsum f32         (zeroed by hist_kernel, atomicAdd by denoise)
//   384: selBin[32] u32     (written by extract_kernel s==0 blocks)
//   512: selKr[32] u32
//  1024: arts, 4 bf16 planes of NPIX packed as u32[2*NPIX] = 50.33 MB
//        ALIASED (dead until denoise writes arts):
//          hist    = arts + 0        : [32][8][4096] u32 = 4 MB
//          members = arts + 4 MB     : [32][8][8192] u32 = 8 MB
//          scount  = arts + 12 MB    : [256] u32
//
// Sync-cost ledger (measured): dispatch boundary ~8-12us; per-block
// __threadfence protocol ~90us (R8); grid.sync ~94us/sync (R5); 768-block
// atomic spin barrier ~280us (R6). => kernel boundaries ONLY.
// Fold ledger (R10): inline 24x-redundant select in denoise = +11us > the
// ~10us boundary it saves. Keep the separate select kernel.
// Spill ledger (R7): duplicated pipeline bodies => ~1GB scratch traffic.
// Occupancy ledger (R9): denoise is VALU-bound — seg16@40%occ = 76.4us vs
// seg32@24%occ = 73us. Keep seg32; attack VALU op count instead (v_pk f32).

__device__ __forceinline__ float med3f(float a, float b, float c) {
    return fmaxf(fminf(a, b), fminf(fmaxf(a, b), c));
}
__device__ __forceinline__ float med5f(float a0, float a1, float a2, float a3, float a4) {
    float mn01 = fminf(a0, a1), mx01 = fmaxf(a0, a1);
    float mn34 = fminf(a3, a4), mx34 = fmaxf(a3, a4);
    return med3f(a2, fmaxf(mn01, mn34), fminf(mx01, mx34));
}
__device__ __forceinline__ u32 packbf(float lo, float hi) {
    u32 a = __float_as_uint(lo), b = __float_as_uint(hi);
    a = (a + 0x7FFFu + ((a >> 16) & 1u)) >> 16;
    b = (b + 0x7FFFu + ((b >> 16) & 1u)) >> 16;
    return a | (b << 16);
}

// inclusive scan over 1024 threads; wtot = 16-entry LDS; all threads must call
__device__ __forceinline__ u32 scan1024(u32 v, u32* wtot) {
    int lane = threadIdx.x & 63, wid = threadIdx.x >> 6;
    u32 inc = v;
    #pragma unroll
    for (int off = 1; off < 64; off <<= 1) {
        u32 o = __shfl_up(inc, off);
        if (lane >= off) inc += o;
    }
    __syncthreads();                 // WAR protection for wtot reuse
    if (lane == 63) wtot[wid] = inc;
    __syncthreads();
    for (int w = 0; w < wid; ++w) inc += wtot[w];
    return inc;
}

// ---------------- median stage 1: per-slice 12-bit histograms ----------------
// 256 blocks = 32 batches x 8 slices; each slice = 24576 floats.

__global__ __launch_bounds__(1024) void hist_kernel(
        const float* __restrict__ x, u32* __restrict__ hist,
        float* __restrict__ madsum) {
    __shared__ u32 lh[16400];    // 4*4100 (lane-spread subs, +4 pad)
    int b = blockIdx.x >> 3, s = blockIdx.x & 7, t = threadIdx.x;
    uint4 z = make_uint4(0u, 0u, 0u, 0u);
    #pragma unroll
    for (int j = 0; j < 4; ++j) ((uint4*)lh)[t + j * 1024] = z;
    if (t < 4) ((uint4*)lh)[4096 + t] = z;
    __syncthreads();
    const float4* xb = (const float4*)(x + (size_t)b * 196608 + s * 24576);
    u32 sub = (u32)(t & 3) * 4100u;
    #pragma unroll
    for (int i = 0; i < 6; ++i) {
        float4 v = xb[t + i * 1024];
        atomicAdd(&lh[sub + (__float_as_uint(fabsf(v.x)) >> 19)], 1u);
        atomicAdd(&lh[sub + (__float_as_uint(fabsf(v.y)) >> 19)], 1u);
        atomicAdd(&lh[sub + (__float_as_uint(fabsf(v.z)) >> 19)], 1u);
        atomicAdd(&lh[sub + (__float_as_uint(fabsf(v.w)) >> 19)], 1u);
    }
    __syncthreads();
    // write bins 4t..4t+3 (sum of 4 subs) as one uint4 — conflict-free reads
    u32 a0 = 0, a1 = 0, a2 = 0, a3 = 0;
    #pragma unroll
    for (int sb = 0; sb < 4; ++sb) {
        uint4 hv = *(const uint4*)&lh[sb * 4100u + (u32)t * 4u];
        a0 += hv.x; a1 += hv.y; a2 += hv.z; a3 += hv.w;
    }
    u32* hb = hist + ((size_t)b * 8 + s) * 4096;
    ((uint4*)hb)[t] = make_uint4(a0, a1, a2, a3);
    if (s == 0 && t == 0 && b == 0) *madsum = 0.0f;
}

// ---------------- median stage 2: find bin, extract member suffixes ----------
// LDS ballot-compaction then ONE coalesced write-out per block. No global
// atomics, no fences — visibility to select via the kernel boundary.

__global__ __launch_bounds__(1024) void extract_kernel(
        const float* __restrict__ x, const u32* __restrict__ hist,
        u32* __restrict__ members, u32* __restrict__ scount,
        u32* __restrict__ selBin, u32* __restrict__ selKr) {
    __shared__ u32 sbuf[8192];
    __shared__ u32 wtot[16];
    __shared__ u32 sBin, lcnt;
    int b = blockIdx.x >> 3, s = blockIdx.x & 7, t = threadIdx.x, lane = t & 63;
    if (t == 0) lcnt = 0u;
    // sum the 8 slice histograms: thread t owns bins 4t..4t+3
    const u32* hb = hist + (size_t)b * 32768;
    u32 s4[4] = {0u, 0u, 0u, 0u};
    #pragma unroll
    for (int sl = 0; sl < 8; ++sl) {
        uint4 h4 = ((const uint4*)(hb + sl * 4096))[t];
        s4[0] += h4.x; s4[1] += h4.y; s4[2] += h4.z; s4[3] += h4.w;
    }
    u32 sum = s4[0] + s4[1] + s4[2] + s4[3];
    u32 inc = scan1024(sum, wtot);
    u32 exc = inc - sum;
    u32 k = 98303u;                  // lower median rank of 196608
    if (exc <= k && k < inc) {
        u32 kr = k - exc;
        int j = 0;
        while (kr >= s4[j]) { kr -= s4[j]; ++j; }
        sBin = (u32)(t * 4 + j);
        if (s == 0) { selBin[b] = (u32)(t * 4 + j); selKr[b] = kr; }
    }
    __syncthreads();
    u32 bin = sBin;
    // sweep the slice (L2/L3-warm from stage 1): ballot-compact 19-bit suffixes
    const float4* xb = (const float4*)(x + (size_t)b * 196608 + s * 24576);
    #pragma unroll 2
    for (int i = 0; i < 6; ++i) {
        float4 v = xb[t + i * 1024];
        float vv[4] = {v.x, v.y, v.z, v.w};
        #pragma unroll
        for (int e = 0; e < 4; ++e) {
            u32 bits = __float_as_uint(fabsf(vv[e]));
            bool is = (bits >> 19) == bin;
            u64 ball = __ballot(is);
            if (ball) {
                u32 cnt = (u32)__popcll(ball);
                u32 base = 0;
                if (lane == 0) base = atomicAdd(&lcnt, cnt);
                base = __shfl(base, 0);
                if (is) {
                    u32 p = base + (u32)__popcll(ball & ((1ull << lane) - 1ull));
                    if (p < 8192u) sbuf[p] = bits & 0x7FFFFu;
                }
            }
        }
    }
    __syncthreads();
    u32 cnt = lcnt; if (cnt > 8192u) cnt = 8192u;
    u32* mb = members + ((size_t)b * 8 + s) * 8192;
    for (u32 i = (u32)t; i < cnt; i += 1024u) mb[i] = sbuf[i];
    if (t == 0) scount[b * 8 + s] = cnt;
}

// ---------------- median stage 3: 19-bit radix select over bin members ------

__global__ __launch_bounds__(1024) void select_kernel(
        const u32* __restrict__ scount, const u32* __restrict__ members,
        const u32* __restrict__ selBin, const u32* __restrict__ selKr,
        float* __restrict__ scale) {
    __shared__ u32 sbuf[8192];
    __shared__ u32 h[128];
    __shared__ u32 wtot[16];
    __shared__ u32 sPfx, sK;
    int b = blockIdx.x, t = threadIdx.x;
    // gather the 8 per-slice member arrays into LDS (packed)
    u32 c[8], off[8], tot = 0u;
    #pragma unroll
    for (int s = 0; s < 8; ++s) {
        c[s] = scount[b * 8 + s];
        off[s] = tot;
        tot += c[s];
    }
    #pragma unroll
    for (int s = 0; s < 8; ++s) {
        const u32* mb = members + ((size_t)b * 8 + s) * 8192;
        for (u32 i = (u32)t; i < c[s]; i += 1024u) {
            u32 p = off[s] + i;
            if (p < 8192u) sbuf[p] = mb[i];
        }
    }
    u32 m = tot; if (m > 8192u) m = 8192u;
    if (t == 0) { sPfx = 0u; sK = selKr[b]; }
    __syncthreads();
    const int shf[3] = {12, 6, 0};
    const int wd[3]  = {7, 6, 6};
    const u32 msk[3] = {127u, 63u, 63u};
    #pragma unroll 1
    for (int rd = 0; rd < 3; ++rd) {
        u32 pfx = sPfx, k2 = sK;
        if (t < 128) h[t] = 0u;
        __syncthreads();
        for (u32 i = (u32)t; i < m; i += 1024u) {
            u32 v = sbuf[i];
            if ((v >> (shf[rd] + wd[rd])) == pfx)
                atomicAdd(&h[(v >> shf[rd]) & msk[rd]], 1u);
        }
        __syncthreads();
        u32 nb = msk[rd] + 1u;
        u32 cc = ((u32)t < nb) ? h[t] : 0u;
        u32 inc2 = scan1024(cc, wtot);
        u32 exc2 = inc2 - cc;
        if ((u32)t < nb && exc2 <= k2 && k2 < inc2) {
            sPfx = (pfx << wd[rd]) | (u32)t;
            sK = k2 - exc2;
        }
        __syncthreads();
    }
    if (t == 0)
        scale[b] = __uint_as_float((selBin[b] << 19) | sPfx) + 1e-8f;
}

// ---------------- denoise: seg=32, packed-f32 (v_pk) stage4 ------------------
// identity: huber_tv(x/s, lam, del) * s == huber_tv(x, lam*s, del*s)
// stage4 rewritten on float2 ext-vectors: hipcc does not auto-pack scalar
// f32 into v_pk_{fma,add,mul}_f32 (full-rate dual f32 on gfx90a+); explicit
// v2f halves the non-transcendental VALU instruction count. Arithmetic is
// op-for-op identical (same fma structure; fadd commutativity only).

__device__ __forceinline__ float dpp_shl1(float v) {   // lane i <- lane i+1 (edge -> 0)
    return __uint_as_float((u32)__builtin_amdgcn_update_dpp(
        0, (int)__float_as_uint(v), 0x130, 0xF, 0xF, true));   // wave_shl:1
}
__device__ __forceinline__ float dpp_shr1(float v) {   // lane i <- lane i-1 (edge -> 0)
    return __uint_as_float((u32)__builtin_amdgcn_update_dpp(
        0, (int)__float_as_uint(v), 0x138, 0xF, 0xF, true));   // wave_shr:1
}

__device__ __forceinline__ v2f hub2(v2f d, float del) {
    v2f den = __builtin_elementwise_abs(d) + (v2f){del, del};
    v2f r;
    r.x = __builtin_amdgcn_rcpf(den.x);
    r.y = __builtin_amdgcn_rcpf(den.y);
    return d * r;
}
__device__ __forceinline__ v2f upd2(v2f b, v2f xn, v2f dv, float lam) {
    v2f t = __builtin_elementwise_fma((v2f){-lam, -lam}, dv, b - xn);
    return __builtin_elementwise_fma((v2f){-0.2f, -0.2f}, t, b);
}

__device__ __forceinline__ float4 stage4(float4 B, float4 C, float4 xn, float4& gyp,
                                         int row, float mR3, float mL0,
                                         float lam, float del) {
    float mr = (row < 255) ? 1.f : 0.f;   // wave-uniform: dy pad 0 at last row
    float m0 = (row == 0) ? 0.f : 1.f;    // div_y[0] = gy[0]
    v2f Bl = {B.x, B.y}, Bh = {B.z, B.w};
    v2f mr2 = {mr, mr}, m02 = {m0, m0};
    v2f gyl = hub2((v2f){C.x, C.y} - Bl, del) * mr2;
    v2f gyh = hub2((v2f){C.z, C.w} - Bh, del) * mr2;
    v2f dvl = gyl - (v2f){gyp.x, gyp.y} * m02;
    v2f dvh = gyh - (v2f){gyp.z, gyp.w} * m02;
    gyp.x = gyl.x; gyp.y = gyl.y; gyp.z = gyh.x; gyp.w = gyh.y;
    float B0n = dpp_shl1(B.x);                  // next lane's col0 (= own col3+1)
    v2f gl = hub2((v2f){B.y, B.z} - Bl, del);                    // {g01, g12}
    v2f gh = hub2((v2f){B.w, B0n} - Bh, del) * (v2f){1.f, mR3};  // {g23, g3n}
    float gp = dpp_shr1(gh.y) * mL0;            // prev lane's g3n; div_x[0] = gx[0]
    v2f totl = (gl - (v2f){gp, gl.x}) + dvl;    // {(g01-gp)+dv0, (g12-g01)+dv1}
    v2f toth = (gh - (v2f){gl.y, gh.x}) + dvh;  // {(g23-g12)+dv2, (g3n-g23)+dv3}
    v2f ol = upd2(Bl, (v2f){xn.x, xn.y}, totl, lam);
    v2f oh = upd2(Bh, (v2f){xn.z, xn.w}, toth, lam);
    float4 o;
    o.x = ol.x; o.y = ol.y; o.z = oh.x; o.w = oh.y;
    return o;
}

__global__ __launch_bounds__(256, 6) void denoise_kernel(
        const float* __restrict__ x, const float* __restrict__ scale,
        u32* __restrict__ arts, float* __restrict__ madsum,
        float4 lam4, float4 del4) {
    __shared__ float sex[2][5][256];   // double-buffered: [parity][0]=x,[1..4]=views
    __shared__ float red[4];
    int t = threadIdx.x, lane = t & 63, wid = t >> 6;   // wid = view
    int img = blockIdx.x >> 3;       // 96 images
    int seg = blockIdx.x & 7;        // 8 row-segments of 32 rows
    float sc = scale[img / 3];
    float lam = ((wid == 0) ? lam4.x : (wid == 1) ? lam4.y : (wid == 2) ? lam4.z : lam4.w) * sc;
    float del = ((wid == 0) ? del4.x : (wid == 1) ? del4.y : (wid == 2) ? del4.z : del4.w) * sc;
    float mR3 = (lane == 63) ? 0.f : 1.f;
    float mL0 = (lane == 0) ? 0.f : 1.f;
    const float4* xp = (const float4*)(x + (size_t)img * 65536) + lane;  // row r: xp[r<<6]
    u32* ap = arts + (size_t)wid * (NPIX / 2) + (size_t)img * 32768 + lane * 2;

    float4 z4 = {0.f, 0.f, 0.f, 0.f};
    float4 cur1 = z4, cur2 = z4, gyp1 = z4, gyp2 = z4, gyp3 = z4;
    float4 n0 = z4, n1 = z4, n2 = z4;
    int out_lo = seg * 32, out_hi = out_lo + 31;
    int rs = (out_lo >= 3) ? out_lo - 3 : 0;   // 3-row pipeline warm-up
    int rend = out_hi + 3;                     // 3-step flush
    float msum = 0.f;

    float4 nl = xp[rs << 6];
    for (int r = rs; r <= rend; ++r) {
        int rn = (r + 1 <= 255) ? r + 1 : 255;
        float4 nxt = xp[rn << 6];   // prefetch (clamped; value unused past row 255)
        int r1 = r - 1, r2 = r - 2, r3 = r - 3;
        float4 x1 = stage4(n0,   nl, n0, gyp1, r1, mR3, mL0, lam, del);
        float4 x2 = stage4(cur1, x1, n1, gyp2, r2, mR3, mL0, lam, del);
        float4 x3 = stage4(cur2, x2, n2, gyp3, r3, mR3, mL0, lam, del);
        cur1 = x1; cur2 = x2;
        if (r3 >= out_lo) {   // block-uniform; r3 <= out_hi by loop bound
            uint2 pk;
            pk.x = packbf(x3.x, x3.y);
            pk.y = packbf(x3.z, x3.w);
            *(uint2*)(ap + (r3 << 7)) = pk;
            // mad exchange, double-buffered by row parity: one sync per row
            int pb = r3 & 1;
            *(float4*)&sex[pb][wid + 1][lane * 4] = x3;
            if (wid == 0) *(float4*)&sex[pb][0][lane * 4] = n2;
            __syncthreads();
            int c = wid * 64 + lane;
            float a0 = sex[pb][0][c], a1 = sex[pb][1][c], a2 = sex[pb][2][c],
                  a3 = sex[pb][3][c], a4 = sex[pb][4][c];
            float med = med5f(a0, a1, a2, a3, a4);
            msum += med5f(fabsf(a0 - med), fabsf(a1 - med), fabsf(a2 - med),
                          fabsf(a3 - med), fabsf(a4 - med));
        }
        n2 = n1; n1 = n0; n0 = nl;
        nl = nxt;
    }
    #pragma unroll
    for (int off = 32; off > 0; off >>= 1) msum += __shfl_down(msum, off);
    if (lane == 0) red[wid] = msum;
    __syncthreads();
    if (t == 0) atomicAdd(madsum, red[0] + red[1] + red[2] + red[3]);
}

// ---------------- fusion: 4 px/thread, 16B loads/stores ----------------

__global__ __launch_bounds__(256) void fuse_kernel(
        const float* __restrict__ x, const u32* __restrict__ artsU,
        const float* __restrict__ madsum, float* __restrict__ out) {
    int t = blockIdx.x * 256 + threadIdx.x;   // t in [0, NPIX/4)
    float floorv = 0.1f * (*madsum) * (1.0f / 6291456.0f);
    float4 xv = ((const float4*)x)[t];
    uint2 q0 = ((const uint2*)(artsU))[t];
    uint2 q1 = ((const uint2*)(artsU + NPIX / 2))[t];
    uint2 q2 = ((const uint2*)(artsU + NPIX))[t];
    uint2 q3 = ((const uint2*)(artsU + 3 * (NPIX / 2)))[t];
    float4 o;
#define FUSE1(res, A0, U0, U1, U2, U3, SH) { \
        float a0 = A0; \
        float a1 = __uint_as_float(SH(U0)), a2 = __uint_as_float(SH(U1)); \
        float a3 = __uint_as_float(SH(U2)), a4 = __uint_as_float(SH(U3)); \
        float med = med5f(a0, a1, a2, a3, a4); \
        float d0 = fabsf(a0 - med), d1 = fabsf(a1 - med), d2 = fabsf(a2 - med); \
        float d3 = fabsf(a3 - med), d4 = fabsf(a4 - med); \
        float mad = med5f(d0, d1, d2, d3, d4); \
        float mm = fmaxf(mad, floorv); \
        float inv = 0.5f / mm; \
        float w0 = __expf(-d0 * inv), w1 = __expf(-d1 * inv), w2 = __expf(-d2 * inv); \
        float w3 = __expf(-d3 * inv), w4 = __expf(-d4 * inv); \
        float swt = w0 + w1 + w2 + w3 + w4; \
        float sva = fmaf(w0, a0, fmaf(w1, a1, fmaf(w2, a2, fmaf(w3, a3, w4 * a4)))); \
        res = sva / (swt + 1e-8f); \
    }
#define LO16(u) ((u) << 16)
#define HI16(u) ((u) & 0xFFFF0000u)
    FUSE1(o.x, xv.x, q0.x, q1.x, q2.x, q3.x, LO16);
    FUSE1(o.y, xv.y, q0.x, q1.x, q2.x, q3.x, HI16);
    FUSE1(o.z, xv.z, q0.y, q1.y, q2.y, q3.y, LO16);
    FUSE1(o.w, xv.w, q0.y, q1.y, q2.y, q3.y, HI16);
#undef FUSE1
#undef LO16
#undef HI16
    ((float4*)out)[t] = o;
}

// ---------------- launch ----------------

extern "C" void kernel_launch(void* const* d_in, const int* in_sizes, int n_in,
                              void* d_out, int out_size, void* d_ws, size_t ws_size,
                              hipStream_t stream) {
    const float* x = (const float*)d_in[0];
    float* out = (float*)d_out;
    char* ws = (char*)d_ws;
    float* scale  = (float*)ws;
    float* madsum = (float*)(ws + 128);
    u32* selBin   = (u32*)(ws + 384);
    u32* selKr    = (u32*)(ws + 512);
    u32* artsU    = (u32*)(ws + 1024);
    // hist (4 MB) + members (8 MB) + scount (1 KB) alias the arts region:
    // all are dead before denoise writes arts.
    u32* hist     = artsU;
    u32* members  = artsU + (size_t)32 * 8 * 4096;
    u32* scount   = members + (size_t)32 * 8 * 8192;

    hist_kernel<<<256, 1024, 0, stream>>>(x, hist, madsum);
    extract_kernel<<<256, 1024, 0, stream>>>(x, hist, members, scount, selBin, selKr);
    select_kernel<<<32, 1024, 0, stream>>>(scount, members, selBin, selKr, scale);

    float lamf[4], delf[4];
    for (int i = 0; i < 4; ++i) {
        double lam = 0.025 + 0.05 * (double)i / 3.0;
        lamf[i] = (float)lam;
        delf[i] = (float)(0.01 * sqrt(lam / (0.05 + 1e-8)));
    }
    float4 lam4 = make_float4(lamf[0], lamf[1], lamf[2], lamf[3]);
    float4 del4 = make_float4(delf[0], delf[1], delf[2], delf[3]);

    denoise_kernel<<<768, 256, 0, stream>>>(x, scale, artsU, madsum, lam4, del4);
    fuse_kernel<<<6144, 256, 0, stream>>>(x, artsU, madsum, out);
}